// Round 2
// baseline (2511.568 us; speedup 1.0000x reference)
//
#include <hip/hip_runtime.h>

// RSSM scan: B=2048, L=64, 128 blocks x 512 thr, block owns 16 rows for all steps.
// v2: register-persisted WG weights (1 tq/wave), persisted biases, unified
// [s,a,0,h] A-tile (double-buffered), fused s'-reparam into P3 (3 barriers/step),
// obs/act/noise prefetch under compute.

typedef unsigned short u16;
typedef unsigned int u32;
typedef __attribute__((ext_vector_type(8))) short short8;
typedef __attribute__((ext_vector_type(4))) float f32x4;

#define LL 64
#define OBS_ 200
#define ACT_ 6
#define STO 30
#define OUTC 350

// packed-weight unit offsets (1 unit = 1KB = 64 lanes x 16B)
#define U_WG   0
#define U_PW1  468
#define U_QW1  559
#define U_PW2  741
#define U_QW2  769
#define U_TOT  797

__device__ __forceinline__ u16 f2b(float f){
  u32 u = __float_as_uint(f);
  u = (u + 0x7fffu + ((u >> 16) & 1u)) >> 16;   // RNE
  return (u16)u;
}
__device__ __forceinline__ float b2f(u16 h){ return __uint_as_float(((u32)h) << 16); }

// LDS XOR swizzle: byte ^= (row&7)<<4 (within 128B blocks; strides sized so the
// XOR block stays in-row).
__device__ __forceinline__ short8 ldA(const u16* buf, int strideB, int r, int colStart){
  return *(const short8*)((const char*)buf + r*strideB + ((colStart*2) ^ ((r & 7) << 4)));
}
__device__ __forceinline__ void st2(u16* buf, int strideB, int r, int c, u16 v){
  *(u16*)((char*)buf + r*strideB + ((c*2) ^ ((r & 7) << 4))) = v;
}
__device__ __forceinline__ u16 ld2(const u16* buf, int strideB, int r, int c){
  return *(const u16*)((const char*)buf + r*strideB + ((c*2) ^ ((r & 7) << 4)));
}
__device__ __forceinline__ short8 ldB(const char* wsb, int unit, int lane){
  return *(const short8*)(wsb + (((size_t)unit) << 10) + ((size_t)lane << 4));
}
__device__ __forceinline__ f32x4 mfma(short8 a, short8 b, f32x4 c){
  return __builtin_amdgcn_mfma_f32_16x16x32_bf16(a, b, c, 0, 0, 0);
}
__device__ __forceinline__ float sigm(float x){ return 1.f / (1.f + __expf(-x)); }
__device__ __forceinline__ float tanhf_(float x){
  x = fminf(fmaxf(x, -15.f), 15.f);
  float e = __expf(-2.f * x);
  return (1.f - e) / (1.f + e);
}
__device__ __forceinline__ float softplus_(float x){
  return (x > 20.f) ? x : log1pf(__expf(x));
}
__device__ __forceinline__ short8 pack8(f32x4 a, f32x4 b){
  short8 v;
  v[0]=(short)f2b(a[0]); v[1]=(short)f2b(a[1]); v[2]=(short)f2b(a[2]); v[3]=(short)f2b(a[3]);
  v[4]=(short)f2b(b[0]); v[5]=(short)f2b(b[1]); v[6]=(short)f2b(b[2]); v[7]=(short)f2b(b[3]);
  return v;
}

// ---------------- weight packing (UNCHANGED, verified round 1) ---------------
__global__ __launch_bounds__(512) void pack_w(
    const float* W_ih, const float* W_hh, const float* pW1f, const float* qW1f,
    const float* pW2f, const float* qW2f, u16* wsu)
{
  int u = blockIdx.x;
  int t = threadIdx.x;
  int lane = t >> 3, j = t & 7;
  int nl = lane & 15, kg = lane >> 4;
  float v = 0.f;
  if (u < U_PW1) {                       // WG
    int nt = u / 9, ks = u % 9;
    int k = ks*32 + kg*8 + j;
    int c = nt*16 + nl;
    int grow, part, coff;
    if (c < 208)      { grow = c;            part = 0; coff = c; }
    else if (c < 416) { grow = 200 + (c-208); part = 0; coff = c-208; }
    else if (c < 624) { grow = 400 + (c-416); part = 1; coff = c-416; }
    else              { grow = 400 + (c-624); part = 2; coff = c-624; }
    if (coff < 200) {
      if (k < 36)                  { if (part != 2) v = W_ih[grow*36 + k]; }
      else if (k >= 64 && k < 264) { if (part != 1) v = W_hh[grow*200 + (k-64)]; }
    }
  } else if (u < U_QW1) {                // PW1
    int uu = u - U_PW1; int nt = uu / 7, ks = uu % 7;
    int k = ks*32 + kg*8 + j; int n = nt*16 + nl;
    if (n < 200 && k < 200) v = pW1f[n*200 + k];
  } else if (u < U_PW2) {                // QW1
    int uu = u - U_QW1; int nt = uu / 14, ks = uu % 14;
    int k = ks*32 + kg*8 + j; int n = nt*16 + nl;
    if (n < 200) {
      if (k < 200) v = qW1f[n*400 + k];
      else if (k >= 224 && k < 424) v = qW1f[n*400 + 200 + (k-224)];
    }
  } else {                               // PW2 / QW2
    bool isQ = (u >= U_QW2);
    int uu = u - (isQ ? U_QW2 : U_PW2); int nt = uu / 7, ks = uu % 7;
    int k = ks*32 + kg*8 + j; int c = nt*16 + nl;
    int row = (c < 32) ? c : 30 + (c - 32);
    bool ok = (c < 32) ? (c < 30) : ((c - 32) < 30);
    const float* W = isQ ? qW2f : pW2f;
    if (ok && k < 200) v = W[row*200 + k];
  }
  wsu[((size_t)u << 9) + lane*8 + j] = f2b(v);
}

// ---------------- main persistent scan kernel ---------------------------------
__global__ __launch_bounds__(512, 2) void rssm_main(
    const float* __restrict__ obs, const float* __restrict__ act,
    const float* __restrict__ noise,
    const float* __restrict__ b_ih, const float* __restrict__ b_hh,
    const float* __restrict__ pb1, const float* __restrict__ pb2,
    const float* __restrict__ qb1, const float* __restrict__ qb2,
    const char* __restrict__ wsb, float* __restrict__ out)
{
  const int tid  = threadIdx.x;
  const int w    = tid >> 6;
  const int lane = tid & 63;
  const int nl   = lane & 15;
  const int kg   = lane >> 4;
  const int m0   = blockIdx.x * 16;

  // sx: [16][288 used /320 alloc] cols: s(0..29) a(30..35) 0(36..63) h(64..263) pad; stride 640B
  // sob: [16][224/256] obs + pad; stride 512B. spp/sqq: [16][224/256]; stride 512B
  __shared__ __align__(16) u16 sxA[16*320];
  __shared__ __align__(16) u16 sxB[16*320];
  __shared__ __align__(16) u16 sob[16*256];
  __shared__ __align__(16) u16 spp[16*256];
  __shared__ __align__(16) u16 sqq[16*256];

  for (int i = tid; i < 16*320; i += 512) { sxA[i]=0; sxB[i]=0; }
  for (int i = tid; i < 16*256; i += 512) { sob[i]=0; spp[i]=0; sqq[i]=0; }

  // ---- persistent WG weights for tq = w (27 units = 108 VGPRs) ----
  short8 pr[9], pz[9], pi[2], ph[7];
#pragma unroll
  for (int ks = 0; ks < 9; ++ks) pr[ks] = ldB(wsb, U_WG + w*9 + ks, lane);
#pragma unroll
  for (int ks = 0; ks < 9; ++ks) pz[ks] = ldB(wsb, U_WG + (13+w)*9 + ks, lane);
  pi[0] = ldB(wsb, U_WG + (26+w)*9 + 0, lane);
  pi[1] = ldB(wsb, U_WG + (26+w)*9 + 1, lane);
#pragma unroll
  for (int ks = 0; ks < 7; ++ks) ph[ks] = ldB(wsb, U_WG + (39+w)*9 + 2 + ks, lane);

  // ---- persistent biases ----
  const int cj1 = w*16 + nl;                       // always < 128 < 200
  const float bR1 = b_ih[cj1]       + b_hh[cj1];
  const float bZ1 = b_ih[200 + cj1] + b_hh[200 + cj1];
  const float bI1 = b_ih[400 + cj1];
  const float bH1 = b_hh[400 + cj1];
  const float qn1b = qb1[cj1];
  const float pn1b = pb1[cj1];

  const bool p1j2  = (w < 5);
  const int  p1tq2 = 8 + w;
  const int  cj2   = p1tq2*16 + nl;
  const bool cj2v  = p1j2 && (cj2 < 200);
  float bR2=0,bZ2=0,bI2=0,bH2=0;
  if (cj2v) {
    bR2 = b_ih[cj2] + b_hh[cj2];
    bZ2 = b_ih[200+cj2] + b_hh[200+cj2];
    bI2 = b_ih[400+cj2];
    bH2 = b_hh[400+cj2];
  }

  const int  p2tq2 = (w==2||w==3) ? (6+w) : (w>=5 ? (5+w) : -1);  // tq 8..12
  const bool p2j2  = (p2tq2 >= 0);
  const int  n2    = p2j2 ? (p2tq2*16 + nl) : 0;
  const bool n2v   = p2j2 && (n2 < 200);
  float qn2b=0, pn2b=0;
  if (n2v) { qn2b = qb1[n2]; pn2b = pb1[n2]; }

  const bool isP3 = (w==0||w==1||w==4||w==5);
  const bool isQ3 = (w >= 4);
  const int  ntA  = w & 1;
  const int  c3   = ntA*16 + nl;
  const bool c3v  = isP3 && (c3 < 30);
  float b3mu=0, b3pre=0;
  if (c3v) { const float* bb = isQ3 ? qb2 : pb2; b3mu = bb[c3]; b3pre = bb[30 + c3]; }

  const bool isStage = !isP3;                      // w in {2,3,6,7}
  const int  sIdx = (w==2)?0:(w==3)?1:(w==6)?2:3;
  const int  sLoc = sIdx*64 + lane;                // 0..255

  __syncthreads();
  // prologue: obs[.,0,.] -> sob ; act[.,0,.] -> sxA cols 30..35 (s0=h0=0 already)
  if (tid < 400) {
    int m = tid / 25, c8 = tid % 25;
    const float* op = obs + (size_t)(m0+m)*LL*OBS_ + c8*8;
    f32x4 a = *(const f32x4*)op, b = *(const f32x4*)(op + 4);
    *(short8*)((char*)sob + m*512 + ((c8*16) ^ ((m & 7) << 4))) = pack8(a, b);
  }
  if (tid < 96) {
    int m = tid / 6, jj = tid % 6;
    st2(sxA, 640, m, 30 + jj, f2b(act[(size_t)(m0+m)*LL*ACT_ + jj]));
  }
  __syncthreads();

  for (int l = 0; l < LL; ++l) {
    u16* sxO = (l & 1) ? sxB : sxA;
    u16* sxN = (l & 1) ? sxA : sxB;

    // ---- eps prefetch (post waves, used in P3) ----
    float ep0=0, ep1=0, ep2=0, ep3=0;
    if (c3v && isQ3) {
      const float* np = noise + (size_t)(m0 + kg*4)*LL*STO + (size_t)l*STO + c3;
      ep0 = np[0];
      ep1 = np[(size_t)LL*STO];
      ep2 = np[2*(size_t)LL*STO];
      ep3 = np[3*(size_t)LL*STO];
    }

    // ================= P1: gate GEMM + GRU update =================
    short8 af[9];
#pragma unroll
    for (int ks = 0; ks < 9; ++ks) af[ks] = ldA(sxO, 640, nl, ks*32 + kg*8);

    f32x4 aR1{0,0,0,0}, aZ1{0,0,0,0}, aI1{0,0,0,0}, aH1{0,0,0,0};
#pragma unroll
    for (int ks = 0; ks < 9; ++ks) {
      aR1 = mfma(af[ks], pr[ks], aR1);
      aZ1 = mfma(af[ks], pz[ks], aZ1);
      if (ks < 2) aI1 = mfma(af[ks], pi[ks], aI1);
      else        aH1 = mfma(af[ks], ph[ks-2], aH1);
    }
    if (p1j2) {   // streamed second tq (waves 0..4)
      f32x4 aR2{0,0,0,0}, aZ2{0,0,0,0}, aI2{0,0,0,0}, aH2{0,0,0,0};
#pragma unroll
      for (int ks = 0; ks < 9; ++ks) {
        aR2 = mfma(af[ks], ldB(wsb, U_WG + p1tq2*9 + ks, lane), aR2);
        aZ2 = mfma(af[ks], ldB(wsb, U_WG + (13+p1tq2)*9 + ks, lane), aZ2);
        if (ks < 2) aI2 = mfma(af[ks], ldB(wsb, U_WG + (26+p1tq2)*9 + ks, lane), aI2);
        else        aH2 = mfma(af[ks], ldB(wsb, U_WG + (39+p1tq2)*9 + ks, lane), aH2);
      }
      if (cj2 < 200) {
#pragma unroll
        for (int i = 0; i < 4; ++i) {
          int m = kg*4 + i;
          float r = sigm(aR2[i] + bR2);
          float z = sigm(aZ2[i] + bZ2);
          float n = tanhf_(aI2[i] + bI2 + r*(aH2[i] + bH2));
          float hold = b2f(ld2(sxO, 640, m, 64 + cj2));
          float hnew = (1.f - z)*n + z*hold;
          st2(sxN, 640, m, 64 + cj2, f2b(hnew));
          out[(size_t)(m0+m)*LL*OUTC + (size_t)l*OUTC + 150 + cj2] = hnew;
        }
      }
    }
#pragma unroll
    for (int i = 0; i < 4; ++i) {
      int m = kg*4 + i;
      float r = sigm(aR1[i] + bR1);
      float z = sigm(aZ1[i] + bZ1);
      float n = tanhf_(aI1[i] + bI1 + r*(aH1[i] + bH1));
      float hold = b2f(ld2(sxO, 640, m, 64 + cj1));
      float hnew = (1.f - z)*n + z*hold;
      st2(sxN, 640, m, 64 + cj1, f2b(hnew));
      out[(size_t)(m0+m)*LL*OUTC + (size_t)l*OUTC + 150 + cj1] = hnew;
    }
    __syncthreads();

    // ================= P2: q1/p1 GEMMs (+ obs/act prefetch for l+1) =========
    f32x4 o0a, o0b, o1a, o1b; float av = 0.f;
    int sm0=0, sc0=0, sm1=0, sc1=0; bool sv0=false, sv1=false;
    if (isStage && (l + 1 < LL)) {
      int j0 = sLoc, j1 = sLoc + 256;
      sv0 = (j0 < 400); sv1 = (j1 < 400);
      if (sv0) {
        sm0 = j0 / 25; sc0 = j0 % 25;
        const float* op = obs + ((size_t)(m0+sm0)*LL + (l+1))*OBS_ + sc0*8;
        o0a = *(const f32x4*)op; o0b = *(const f32x4*)(op + 4);
      }
      if (sv1) {
        sm1 = j1 / 25; sc1 = j1 % 25;
        const float* op = obs + ((size_t)(m0+sm1)*LL + (l+1))*OBS_ + sc1*8;
        o1a = *(const f32x4*)op; o1b = *(const f32x4*)(op + 4);
      }
      if (w < 4) {  // w in {2,3}: act prefetch
        int l2 = (w-2)*64 + lane;
        if (l2 < 96) av = act[((size_t)(m0 + l2/6)*LL + (l+1))*ACT_ + (l2 % 6)];
      }
    }

    short8 ao[7], ah[7];
#pragma unroll
    for (int ks = 0; ks < 7; ++ks) ao[ks] = ldA(sob, 512, nl, ks*32 + kg*8);
#pragma unroll
    for (int ks = 0; ks < 7; ++ks) ah[ks] = ldA(sxN, 640, nl, 64 + ks*32 + kg*8);

    f32x4 aq1{0,0,0,0}, ap1{0,0,0,0};
#pragma unroll
    for (int ks = 0; ks < 7; ++ks) {
      aq1 = mfma(ao[ks], ldB(wsb, U_QW1 + w*14 + ks,     lane), aq1);
      aq1 = mfma(ah[ks], ldB(wsb, U_QW1 + w*14 + 7 + ks, lane), aq1);
      ap1 = mfma(ah[ks], ldB(wsb, U_PW1 + w*7 + ks,      lane), ap1);
    }
#pragma unroll
    for (int i = 0; i < 4; ++i) {
      int m = kg*4 + i;
      float vq = aq1[i] + qn1b; st2(sqq, 512, m, cj1, f2b(vq > 0.f ? vq : 0.f));
      float vp = ap1[i] + pn1b; st2(spp, 512, m, cj1, f2b(vp > 0.f ? vp : 0.f));
    }
    if (p2j2) {
      f32x4 aq2{0,0,0,0}, ap2{0,0,0,0};
#pragma unroll
      for (int ks = 0; ks < 7; ++ks) {
        aq2 = mfma(ao[ks], ldB(wsb, U_QW1 + p2tq2*14 + ks,     lane), aq2);
        aq2 = mfma(ah[ks], ldB(wsb, U_QW1 + p2tq2*14 + 7 + ks, lane), aq2);
        ap2 = mfma(ah[ks], ldB(wsb, U_PW1 + p2tq2*7 + ks,      lane), ap2);
      }
      if (n2 < 200) {
#pragma unroll
        for (int i = 0; i < 4; ++i) {
          int m = kg*4 + i;
          float vq = aq2[i] + qn2b; st2(sqq, 512, m, n2, f2b(vq > 0.f ? vq : 0.f));
          float vp = ap2[i] + pn2b; st2(spp, 512, m, n2, f2b(vp > 0.f ? vp : 0.f));
        }
      }
    }
    __syncthreads();

    // ================= P3: heads + reparam (waves 0,1,4,5) / staging ========
    if (isP3) {
      const u16* s3 = isQ3 ? sqq : spp;
      const int  ub = isQ3 ? U_QW2 : U_PW2;
      f32x4 a0{0,0,0,0}, a1{0,0,0,0};
#pragma unroll
      for (int ks = 0; ks < 7; ++ks) {
        short8 a3 = ldA(s3, 512, nl, ks*32 + kg*8);
        a0 = mfma(a3, ldB(wsb, ub + ntA*7 + ks,     lane), a0);
        a1 = mfma(a3, ldB(wsb, ub + (ntA+2)*7 + ks, lane), a1);
      }
      if (c3 < 30) {
        float eps[4] = {ep0, ep1, ep2, ep3};
#pragma unroll
        for (int i = 0; i < 4; ++i) {
          int m = kg*4 + i;
          size_t ob = (size_t)(m0+m)*LL*OUTC + (size_t)l*OUTC;
          float mu = a0[i] + b3mu;
          float sp = softplus_(a1[i] + b3pre) + 1e-5f;
          float sd = fmaxf(sp, 1e-4f);
          if (isQ3) {
            out[ob +  60 + c3] = mu;
            out[ob +  90 + c3] = sd;
            float s = mu + sd*eps[i];
            out[ob + 120 + c3] = s;
            st2(sxN, 640, m, c3, f2b(s));
          } else {
            out[ob +  0 + c3] = mu;
            out[ob + 30 + c3] = sd;
          }
        }
      }
    } else if (l + 1 < LL) {   // stage waves: land prefetched obs/act
      if (sv0) *(short8*)((char*)sob + sm0*512 + ((sc0*16) ^ ((sm0 & 7) << 4))) = pack8(o0a, o0b);
      if (sv1) *(short8*)((char*)sob + sm1*512 + ((sc1*16) ^ ((sm1 & 7) << 4))) = pack8(o1a, o1b);
      if (w < 4) {
        int l2 = (w-2)*64 + lane;
        if (l2 < 96) st2(sxN, 640, l2/6, 30 + (l2 % 6), f2b(av));
      }
    }
    __syncthreads();
  }
}

extern "C" void kernel_launch(void* const* d_in, const int* in_sizes, int n_in,
                              void* d_out, int out_size, void* d_ws, size_t ws_size,
                              hipStream_t stream) {
  const float* obs   = (const float*)d_in[0];
  const float* act   = (const float*)d_in[1];
  const float* noise = (const float*)d_in[2];
  const float* W_ih  = (const float*)d_in[3];
  const float* b_ih  = (const float*)d_in[4];
  const float* W_hh  = (const float*)d_in[5];
  const float* b_hh  = (const float*)d_in[6];
  const float* pW1   = (const float*)d_in[7];
  const float* pb1   = (const float*)d_in[8];
  const float* pW2   = (const float*)d_in[9];
  const float* pb2   = (const float*)d_in[10];
  const float* qW1   = (const float*)d_in[11];
  const float* qb1   = (const float*)d_in[12];
  const float* qW2   = (const float*)d_in[13];
  const float* qb2   = (const float*)d_in[14];
  float* out = (float*)d_out;

  pack_w<<<U_TOT, 512, 0, stream>>>(W_ih, W_hh, pW1, qW1, pW2, qW2, (u16*)d_ws);
  rssm_main<<<128, 512, 0, stream>>>(obs, act, noise, b_ih, b_hh,
                                     pb1, pb2, qb1, qb2,
                                     (const char*)d_ws, out);
}

// Round 3
// 2375.978 us; speedup vs baseline: 1.0571x; 1.0571x over previous
//
#include <hip/hip_runtime.h>

// RSSM scan: B=2048, L=64. v3: 64 blocks x 1024 thr (16 waves), M=32 rows/block,
// 4 waves/SIMD, balanced 1-job-per-wave phases, dedicated stager waves, no
// register-persisted weights (round-2 spill lesson). 3 barriers/step.

typedef unsigned short u16;
typedef unsigned int u32;
typedef __attribute__((ext_vector_type(8))) short short8;
typedef __attribute__((ext_vector_type(4))) float f32x4;

#define LL 64
#define OBS_ 200
#define ACT_ 6
#define STO 30
#define OUTC 350

// packed-weight unit offsets (1 unit = 1KB = 64 lanes x 16B)
#define U_WG   0
#define U_PW1  468
#define U_QW1  559
#define U_PW2  741
#define U_QW2  769
#define U_TOT  797

__device__ __forceinline__ u16 f2b(float f){
  u32 u = __float_as_uint(f);
  u = (u + 0x7fffu + ((u >> 16) & 1u)) >> 16;   // RNE
  return (u16)u;
}
__device__ __forceinline__ float b2f(u16 h){ return __uint_as_float(((u32)h) << 16); }

// stride-512 buffers: swizzle byte ^= (r&7)<<4 (512 = 4x128, XOR stays in-row)
__device__ __forceinline__ short8 ldA7(const u16* buf, int r, int colStart){
  return *(const short8*)((const char*)buf + r*512 + ((colStart*2) ^ ((r & 7) << 4)));
}
__device__ __forceinline__ void st27(u16* buf, int r, int c, u16 v){
  *(u16*)((char*)buf + r*512 + ((c*2) ^ ((r & 7) << 4))) = v;
}
__device__ __forceinline__ u16 ld27(const u16* buf, int r, int c){
  return *(const u16*)((const char*)buf + r*512 + ((c*2) ^ ((r & 7) << 4)));
}
// stride-448 buffer (sqq): swizzle byte ^= (r&3)<<4 (448 = 7x64)
__device__ __forceinline__ short8 ldA3(const u16* buf, int r, int colStart){
  return *(const short8*)((const char*)buf + r*448 + ((colStart*2) ^ ((r & 3) << 4)));
}
__device__ __forceinline__ void st23(u16* buf, int r, int c, u16 v){
  *(u16*)((char*)buf + r*448 + ((c*2) ^ ((r & 3) << 4))) = v;
}
__device__ __forceinline__ short8 ldB(const char* wsb, int unit, int lane){
  return *(const short8*)(wsb + (((size_t)unit) << 10) + ((size_t)lane << 4));
}
__device__ __forceinline__ f32x4 mfma(short8 a, short8 b, f32x4 c){
  return __builtin_amdgcn_mfma_f32_16x16x32_bf16(a, b, c, 0, 0, 0);
}
__device__ __forceinline__ float sigm(float x){ return 1.f / (1.f + __expf(-x)); }
__device__ __forceinline__ float tanhf_(float x){
  x = fminf(fmaxf(x, -15.f), 15.f);
  float e = __expf(-2.f * x);
  return (1.f - e) / (1.f + e);
}
__device__ __forceinline__ float softplus_(float x){
  return (x > 20.f) ? x : log1pf(__expf(x));
}
__device__ __forceinline__ short8 pack8(f32x4 a, f32x4 b){
  short8 v;
  v[0]=(short)f2b(a[0]); v[1]=(short)f2b(a[1]); v[2]=(short)f2b(a[2]); v[3]=(short)f2b(a[3]);
  v[4]=(short)f2b(b[0]); v[5]=(short)f2b(b[1]); v[6]=(short)f2b(b[2]); v[7]=(short)f2b(b[3]);
  return v;
}

// ---------------- weight packing (UNCHANGED, verified round 1) ---------------
__global__ __launch_bounds__(512) void pack_w(
    const float* W_ih, const float* W_hh, const float* pW1f, const float* qW1f,
    const float* pW2f, const float* qW2f, u16* wsu)
{
  int u = blockIdx.x;
  int t = threadIdx.x;
  int lane = t >> 3, j = t & 7;
  int nl = lane & 15, kg = lane >> 4;
  float v = 0.f;
  if (u < U_PW1) {                       // WG
    int nt = u / 9, ks = u % 9;
    int k = ks*32 + kg*8 + j;
    int c = nt*16 + nl;
    int grow, part, coff;
    if (c < 208)      { grow = c;            part = 0; coff = c; }
    else if (c < 416) { grow = 200 + (c-208); part = 0; coff = c-208; }
    else if (c < 624) { grow = 400 + (c-416); part = 1; coff = c-416; }
    else              { grow = 400 + (c-624); part = 2; coff = c-624; }
    if (coff < 200) {
      if (k < 36)                  { if (part != 2) v = W_ih[grow*36 + k]; }
      else if (k >= 64 && k < 264) { if (part != 1) v = W_hh[grow*200 + (k-64)]; }
    }
  } else if (u < U_QW1) {                // PW1
    int uu = u - U_PW1; int nt = uu / 7, ks = uu % 7;
    int k = ks*32 + kg*8 + j; int n = nt*16 + nl;
    if (n < 200 && k < 200) v = pW1f[n*200 + k];
  } else if (u < U_PW2) {                // QW1
    int uu = u - U_QW1; int nt = uu / 14, ks = uu % 14;
    int k = ks*32 + kg*8 + j; int n = nt*16 + nl;
    if (n < 200) {
      if (k < 200) v = qW1f[n*400 + k];
      else if (k >= 224 && k < 424) v = qW1f[n*400 + 200 + (k-224)];
    }
  } else {                               // PW2 / QW2
    bool isQ = (u >= U_QW2);
    int uu = u - (isQ ? U_QW2 : U_PW2); int nt = uu / 7, ks = uu % 7;
    int k = ks*32 + kg*8 + j; int c = nt*16 + nl;
    int row = (c < 32) ? c : 30 + (c - 32);
    bool ok = (c < 32) ? (c < 30) : ((c - 32) < 30);
    const float* W = isQ ? qW2f : pW2f;
    if (ok && k < 200) v = W[row*200 + k];
  }
  wsu[((size_t)u << 9) + lane*8 + j] = f2b(v);
}

// ---------------- main persistent scan kernel ---------------------------------
__global__ __launch_bounds__(1024) void rssm_main(
    const float* __restrict__ obs, const float* __restrict__ act,
    const float* __restrict__ noise,
    const float* __restrict__ b_ih, const float* __restrict__ b_hh,
    const float* __restrict__ pb1, const float* __restrict__ pb2,
    const float* __restrict__ qb1, const float* __restrict__ qb2,
    const char* __restrict__ wsb, float* __restrict__ out)
{
  const int tid  = threadIdx.x;
  const int w    = tid >> 6;      // wave 0..15
  const int lane = tid & 63;
  const int nl   = lane & 15;
  const int kg   = lane >> 4;
  const int m0   = blockIdx.x * 32;

  // h0/h1: [32][256] u16 stride 512B; cols: h 0..199 | s 200..229 | a 230..235 | junk
  //   (all pad/junk columns are zero-weighted in the packed weights)
  // sob: [32][256] obs 0..199 + zeros.  sqq: [32][224] stride 448B (r&3 swizzle).
  // spp overlays hO (old-h dead after P1).
  __shared__ __align__(16) u16 h0 [32*256];
  __shared__ __align__(16) u16 h1 [32*256];
  __shared__ __align__(16) u16 sob[32*256];
  __shared__ __align__(16) u16 sqq[32*224];

  for (int i = tid; i < 32*256; i += 1024) { h0[i]=0; h1[i]=0; sob[i]=0; }
  for (int i = tid; i < 32*224; i += 1024) sqq[i]=0;

  // ---- per-wave role constants & persisted biases (scalars only) ----
  const bool p12j = (w < 13);                 // P1/P2 job: tq = w
  const int  cj   = w*16 + nl;
  const bool cjv  = p12j && (cj < 200);
  float bR1=0,bZ1=0,bI1=0,bH1=0,qn1b=0,pn1b=0;
  if (cjv) {
    bR1 = b_ih[cj]       + b_hh[cj];
    bZ1 = b_ih[200 + cj] + b_hh[200 + cj];
    bI1 = b_ih[400 + cj];
    bH1 = b_hh[400 + cj];
    qn1b = qb1[cj];
    pn1b = pb1[cj];
  }
  const bool isP3 = (w < 8);
  const bool isQ3 = (w >= 4);
  const int  ntA  = w & 1;
  const int  mh3  = (w >> 1) & 1;
  const int  c3   = ntA*16 + nl;
  const bool c3v  = isP3 && (c3 < 30);
  float b3mu=0, b3pre=0;
  if (c3v) { const float* bb = isQ3 ? qb2 : pb2; b3mu = bb[c3]; b3pre = bb[30 + c3]; }

  const bool isStage = (w >= 13);
  const int  lg = (w - 13)*64 + lane;         // 0..191 for stagers

  __syncthreads();
  // ---- prologue: obs[.,0,.] -> sob ; act[.,0,.] -> h0 cols 230..235 ----
  for (int c = tid; c < 800; c += 1024) {
    int row = c / 25, ch = c % 25;
    const float* op = obs + (size_t)(m0+row)*LL*OBS_ + ch*8;
    f32x4 a = *(const f32x4*)op, b = *(const f32x4*)(op + 4);
    *(short8*)((char*)sob + row*512 + ((ch*16) ^ ((row & 7) << 4))) = pack8(a, b);
  }
  if (tid < 192) {
    int row = tid / 6, j = tid % 6;
    st27(h0, row, 230 + j, f2b(act[(size_t)(m0+row)*LL*ACT_ + j]));
  }
  __syncthreads();

#pragma unroll 1
  for (int l = 0; l < LL; ++l) {
    u16* hO = (l & 1) ? h1 : h0;
    u16* hN = (l & 1) ? h0 : h1;
    const size_t outB = (size_t)l*OUTC;

    // ---- step-start prefetches (in flight under P1/P2 compute) ----
    float ep0=0, ep1=0, ep2=0, ep3=0;
    if (c3v && isQ3) {
      const float* np = noise + (size_t)(m0 + mh3*16 + kg*4)*LL*STO + (size_t)l*STO + c3;
      ep0 = np[0];
      ep1 = np[(size_t)LL*STO];
      ep2 = np[2*(size_t)LL*STO];
      ep3 = np[3*(size_t)LL*STO];
    }
    f32x4 oa0{},ob0{},oa1{},ob1{},oa2{},ob2{},oa3{},ob3{},oa4{},ob4{};
    float av = 0.f;
    if (isStage && (l + 1 < LL)) {
      {
        int c = lg;            int row=c/25, ch=c%25;   // c < 800 always
        const float* op = obs + ((size_t)(m0+row)*LL + (l+1))*OBS_ + ch*8;
        oa0 = *(const f32x4*)op; ob0 = *(const f32x4*)(op+4);
      }
      {
        int c = lg + 192;      int row=c/25, ch=c%25;
        const float* op = obs + ((size_t)(m0+row)*LL + (l+1))*OBS_ + ch*8;
        oa1 = *(const f32x4*)op; ob1 = *(const f32x4*)(op+4);
      }
      {
        int c = lg + 384;      int row=c/25, ch=c%25;
        const float* op = obs + ((size_t)(m0+row)*LL + (l+1))*OBS_ + ch*8;
        oa2 = *(const f32x4*)op; ob2 = *(const f32x4*)(op+4);
      }
      {
        int c = lg + 576;      int row=c/25, ch=c%25;
        const float* op = obs + ((size_t)(m0+row)*LL + (l+1))*OBS_ + ch*8;
        oa3 = *(const f32x4*)op; ob3 = *(const f32x4*)(op+4);
      }
      if (lg + 768 < 800) {
        int c = lg + 768;      int row=c/25, ch=c%25;
        const float* op = obs + ((size_t)(m0+row)*LL + (l+1))*OBS_ + ch*8;
        oa4 = *(const f32x4*)op; ob4 = *(const f32x4*)(op+4);
      }
      av = act[((size_t)(m0 + lg/6)*LL + (l+1))*ACT_ + (lg % 6)];
    }

    // ================= P1: gate GEMM + GRU update (waves 0..12) =============
    if (p12j) {
      f32x4 aR[2]={{0,0,0,0},{0,0,0,0}}, aZ[2]={{0,0,0,0},{0,0,0,0}};
      f32x4 aI[2]={{0,0,0,0},{0,0,0,0}}, aH[2]={{0,0,0,0},{0,0,0,0}};
#pragma unroll
      for (int ks = 0; ks < 9; ++ks) {
        const int col = (ks < 2) ? (200 + ks*32 + kg*8) : ((ks-2)*32 + kg*8);
        short8 a0 = ldA7(hO, nl,      col);
        short8 a1 = ldA7(hO, nl + 16, col);
        short8 bR = ldB(wsb, U_WG + w*9 + ks,      lane);
        short8 bZ = ldB(wsb, U_WG + (13+w)*9 + ks, lane);
        aR[0] = mfma(a0, bR, aR[0]); aR[1] = mfma(a1, bR, aR[1]);
        aZ[0] = mfma(a0, bZ, aZ[0]); aZ[1] = mfma(a1, bZ, aZ[1]);
        if (ks < 2) {
          short8 bI = ldB(wsb, U_WG + (26+w)*9 + ks, lane);
          aI[0] = mfma(a0, bI, aI[0]); aI[1] = mfma(a1, bI, aI[1]);
        } else {
          short8 bH = ldB(wsb, U_WG + (39+w)*9 + ks, lane);
          aH[0] = mfma(a0, bH, aH[0]); aH[1] = mfma(a1, bH, aH[1]);
        }
      }
      if (cj < 200) {
#pragma unroll
        for (int mh = 0; mh < 2; ++mh) {
#pragma unroll
          for (int i = 0; i < 4; ++i) {
            int m = mh*16 + kg*4 + i;
            float r = sigm(aR[mh][i] + bR1);
            float z = sigm(aZ[mh][i] + bZ1);
            float n = tanhf_(aI[mh][i] + bI1 + r*(aH[mh][i] + bH1));
            float hold = b2f(ld27(hO, m, cj));
            float hnew = (1.f - z)*n + z*hold;
            st27(hN, m, cj, f2b(hnew));
            out[(size_t)(m0+m)*LL*OUTC + outB + 150 + cj] = hnew;
          }
        }
      }
    }
    __syncthreads();

    // ================= P2: q1 ([obs,h']) and p1 (h') GEMMs (waves 0..12) ====
    if (p12j) {
      f32x4 aq[2]={{0,0,0,0},{0,0,0,0}}, ap[2]={{0,0,0,0},{0,0,0,0}};
#pragma unroll
      for (int ks = 0; ks < 7; ++ks) {
        const int col = ks*32 + kg*8;
        short8 o0 = ldA7(sob, nl,      col);
        short8 o1 = ldA7(sob, nl + 16, col);
        short8 g0 = ldA7(hN,  nl,      col);
        short8 g1 = ldA7(hN,  nl + 16, col);
        short8 bq1 = ldB(wsb, U_QW1 + w*14 + ks,     lane);
        short8 bq2 = ldB(wsb, U_QW1 + w*14 + 7 + ks, lane);
        short8 bp  = ldB(wsb, U_PW1 + w*7 + ks,      lane);
        aq[0] = mfma(o0, bq1, aq[0]); aq[1] = mfma(o1, bq1, aq[1]);
        aq[0] = mfma(g0, bq2, aq[0]); aq[1] = mfma(g1, bq2, aq[1]);
        ap[0] = mfma(g0, bp,  ap[0]); ap[1] = mfma(g1, bp,  ap[1]);
      }
      if (cj < 200) {
#pragma unroll
        for (int mh = 0; mh < 2; ++mh) {
#pragma unroll
          for (int i = 0; i < 4; ++i) {
            int m = mh*16 + kg*4 + i;
            float vq = aq[mh][i] + qn1b;
            st23(sqq, m, cj, f2b(vq > 0.f ? vq : 0.f));
            float vp = ap[mh][i] + pn1b;
            st27(hO, m, cj, f2b(vp > 0.f ? vp : 0.f));   // spp overlay into old-h
          }
        }
      }
    }
    __syncthreads();

    // ================= P3: heads + reparam (waves 0..7); stagers land =======
    if (isP3) {
      const int ub = isQ3 ? U_QW2 : U_PW2;
      f32x4 a0{0,0,0,0}, a1{0,0,0,0};
#pragma unroll
      for (int ks = 0; ks < 7; ++ks) {
        const int col = ks*32 + kg*8;
        short8 af = isQ3 ? ldA3(sqq, mh3*16 + nl, col)
                         : ldA7(hO,  mh3*16 + nl, col);
        a0 = mfma(af, ldB(wsb, ub + ntA*7 + ks,     lane), a0);
        a1 = mfma(af, ldB(wsb, ub + (ntA+2)*7 + ks, lane), a1);
      }
      if (c3 < 30) {
        float eps[4] = {ep0, ep1, ep2, ep3};
#pragma unroll
        for (int i = 0; i < 4; ++i) {
          int m = mh3*16 + kg*4 + i;
          size_t ob = (size_t)(m0+m)*LL*OUTC + outB;
          float mu = a0[i] + b3mu;
          float sp = softplus_(a1[i] + b3pre) + 1e-5f;
          float sd = fmaxf(sp, 1e-4f);
          if (isQ3) {
            out[ob +  60 + c3] = mu;
            out[ob +  90 + c3] = sd;
            float s = mu + sd*eps[i];
            out[ob + 120 + c3] = s;
            st27(hN, m, 200 + c3, f2b(s));
          } else {
            out[ob +  0 + c3] = mu;
            out[ob + 30 + c3] = sd;
          }
        }
      }
    } else if (isStage && (l + 1 < LL)) {
      {
        int c = lg;       int row=c/25, ch=c%25;
        *(short8*)((char*)sob + row*512 + ((ch*16) ^ ((row&7)<<4))) = pack8(oa0, ob0);
      }
      {
        int c = lg + 192; int row=c/25, ch=c%25;
        *(short8*)((char*)sob + row*512 + ((ch*16) ^ ((row&7)<<4))) = pack8(oa1, ob1);
      }
      {
        int c = lg + 384; int row=c/25, ch=c%25;
        *(short8*)((char*)sob + row*512 + ((ch*16) ^ ((row&7)<<4))) = pack8(oa2, ob2);
      }
      {
        int c = lg + 576; int row=c/25, ch=c%25;
        *(short8*)((char*)sob + row*512 + ((ch*16) ^ ((row&7)<<4))) = pack8(oa3, ob3);
      }
      if (lg + 768 < 800) {
        int c = lg + 768; int row=c/25, ch=c%25;
        *(short8*)((char*)sob + row*512 + ((ch*16) ^ ((row&7)<<4))) = pack8(oa4, ob4);
      }
      st27(hN, lg/6, 230 + (lg % 6), f2b(av));
    }
    __syncthreads();
  }
}

extern "C" void kernel_launch(void* const* d_in, const int* in_sizes, int n_in,
                              void* d_out, int out_size, void* d_ws, size_t ws_size,
                              hipStream_t stream) {
  const float* obs   = (const float*)d_in[0];
  const float* act   = (const float*)d_in[1];
  const float* noise = (const float*)d_in[2];
  const float* W_ih  = (const float*)d_in[3];
  const float* b_ih  = (const float*)d_in[4];
  const float* W_hh  = (const float*)d_in[5];
  const float* b_hh  = (const float*)d_in[6];
  const float* pW1   = (const float*)d_in[7];
  const float* pb1   = (const float*)d_in[8];
  const float* pW2   = (const float*)d_in[9];
  const float* pb2   = (const float*)d_in[10];
  const float* qW1   = (const float*)d_in[11];
  const float* qb1   = (const float*)d_in[12];
  const float* qW2   = (const float*)d_in[13];
  const float* qb2   = (const float*)d_in[14];
  float* out = (float*)d_out;

  pack_w<<<U_TOT, 512, 0, stream>>>(W_ih, W_hh, pW1, qW1, pW2, qW2, (u16*)d_ws);
  rssm_main<<<64, 1024, 0, stream>>>(obs, act, noise, b_ih, b_hh,
                                     pb1, pb2, qb1, qb2,
                                     (const char*)d_ws, out);
}

// Round 4
// 1363.447 us; speedup vs baseline: 1.8421x; 1.7426x over previous
//
#include <hip/hip_runtime.h>

// RSSM scan v4: decompose into
//   pack_w  : weight repack (verified r1)
//   qx_k    : PARALLEL obs@qW1_obs + qb1 for all B*L rows -> ws (bf16)
//   rssm_seq: sequential scan, GRU + posterior chain only. 128 blocks x 16
//             waves, M=16 rows, one P1 job per wave, qx/act staged by waves
//             13-15 under compute. 3 barriers/step.
//   prior_k : PARALLEL prior MLP for all B*L rows (reads h from out)

typedef unsigned short u16;
typedef unsigned int u32;
typedef __attribute__((ext_vector_type(8))) short short8;
typedef __attribute__((ext_vector_type(4))) float f32x4;

#define LL 64
#define OBS_ 200
#define ACT_ 6
#define STO 30
#define OUTC 350

// packed-weight unit offsets (1 unit = 1KB = 64 lanes x 16B)
#define U_WG   0
#define U_PW1  468
#define U_QW1  559
#define U_PW2  741
#define U_QW2  769
#define U_TOT  797
#define QX_OFF (1u << 20)

__device__ __forceinline__ u16 f2b(float f){
  u32 u = __float_as_uint(f);
  u = (u + 0x7fffu + ((u >> 16) & 1u)) >> 16;   // RNE
  return (u16)u;
}
__device__ __forceinline__ float b2f(u16 h){ return __uint_as_float(((u32)h) << 16); }

// stride-512B tiles (h): swizzle byte ^= (r&7)<<4
__device__ __forceinline__ short8 ldA7(const u16* buf, int r, int colStart){
  return *(const short8*)((const char*)buf + r*512 + ((colStart*2) ^ ((r & 7) << 4)));
}
__device__ __forceinline__ void st27(u16* buf, int r, int c, u16 v){
  *(u16*)((char*)buf + r*512 + ((c*2) ^ ((r & 7) << 4))) = v;
}
__device__ __forceinline__ u16 ld27(const u16* buf, int r, int c){
  return *(const u16*)((const char*)buf + r*512 + ((c*2) ^ ((r & 7) << 4)));
}
// stride-448B tiles (sqq/sqx/sob/shh/spp): swizzle byte ^= (r&3)<<4
__device__ __forceinline__ short8 ldA3(const u16* buf, int r, int colStart){
  return *(const short8*)((const char*)buf + r*448 + ((colStart*2) ^ ((r & 3) << 4)));
}
__device__ __forceinline__ void st23(u16* buf, int r, int c, u16 v){
  *(u16*)((char*)buf + r*448 + ((c*2) ^ ((r & 3) << 4))) = v;
}
__device__ __forceinline__ u16 ld23(const u16* buf, int r, int c){
  return *(const u16*)((const char*)buf + r*448 + ((c*2) ^ ((r & 3) << 4)));
}
__device__ __forceinline__ void st8_3(u16* buf, int r, int c8, short8 v){
  *(short8*)((char*)buf + r*448 + ((c8*16) ^ ((r & 3) << 4))) = v;
}
__device__ __forceinline__ short8 ldB(const char* wsb, int unit, int lane){
  return *(const short8*)(wsb + (((size_t)unit) << 10) + ((size_t)lane << 4));
}
__device__ __forceinline__ f32x4 mfma(short8 a, short8 b, f32x4 c){
  return __builtin_amdgcn_mfma_f32_16x16x32_bf16(a, b, c, 0, 0, 0);
}
__device__ __forceinline__ float sigm(float x){ return 1.f / (1.f + __expf(-x)); }
__device__ __forceinline__ float tanhf_(float x){
  x = fminf(fmaxf(x, -15.f), 15.f);
  float e = __expf(-2.f * x);
  return (1.f - e) / (1.f + e);
}
__device__ __forceinline__ float softplus_(float x){
  return (x > 20.f) ? x : log1pf(__expf(x));
}
__device__ __forceinline__ short8 pack8(f32x4 a, f32x4 b){
  short8 v;
  v[0]=(short)f2b(a[0]); v[1]=(short)f2b(a[1]); v[2]=(short)f2b(a[2]); v[3]=(short)f2b(a[3]);
  v[4]=(short)f2b(b[0]); v[5]=(short)f2b(b[1]); v[6]=(short)f2b(b[2]); v[7]=(short)f2b(b[3]);
  return v;
}

// ---------------- weight packing (UNCHANGED, verified round 1) ---------------
__global__ __launch_bounds__(512) void pack_w(
    const float* W_ih, const float* W_hh, const float* pW1f, const float* qW1f,
    const float* pW2f, const float* qW2f, u16* wsu)
{
  int u = blockIdx.x;
  int t = threadIdx.x;
  int lane = t >> 3, j = t & 7;
  int nl = lane & 15, kg = lane >> 4;
  float v = 0.f;
  if (u < U_PW1) {                       // WG
    int nt = u / 9, ks = u % 9;
    int k = ks*32 + kg*8 + j;
    int c = nt*16 + nl;
    int grow, part, coff;
    if (c < 208)      { grow = c;            part = 0; coff = c; }
    else if (c < 416) { grow = 200 + (c-208); part = 0; coff = c-208; }
    else if (c < 624) { grow = 400 + (c-416); part = 1; coff = c-416; }
    else              { grow = 400 + (c-624); part = 2; coff = c-624; }
    if (coff < 200) {
      if (k < 36)                  { if (part != 2) v = W_ih[grow*36 + k]; }
      else if (k >= 64 && k < 264) { if (part != 1) v = W_hh[grow*200 + (k-64)]; }
    }
  } else if (u < U_QW1) {                // PW1
    int uu = u - U_PW1; int nt = uu / 7, ks = uu % 7;
    int k = ks*32 + kg*8 + j; int n = nt*16 + nl;
    if (n < 200 && k < 200) v = pW1f[n*200 + k];
  } else if (u < U_PW2) {                // QW1
    int uu = u - U_QW1; int nt = uu / 14, ks = uu % 14;
    int k = ks*32 + kg*8 + j; int n = nt*16 + nl;
    if (n < 200) {
      if (k < 200) v = qW1f[n*400 + k];
      else if (k >= 224 && k < 424) v = qW1f[n*400 + 200 + (k-224)];
    }
  } else {                               // PW2 / QW2
    bool isQ = (u >= U_QW2);
    int uu = u - (isQ ? U_QW2 : U_PW2); int nt = uu / 7, ks = uu % 7;
    int k = ks*32 + kg*8 + j; int c = nt*16 + nl;
    int row = (c < 32) ? c : 30 + (c - 32);
    bool ok = (c < 32) ? (c < 30) : ((c - 32) < 30);
    const float* W = isQ ? qW2f : pW2f;
    if (ok && k < 200) v = W[row*200 + k];
  }
  wsu[((size_t)u << 9) + lane*8 + j] = f2b(v);
}

// ---------------- qx kernel: qx[r][n] = obs[r]@qW1_obs^T + qb1 (bf16) --------
__global__ __launch_bounds__(512) void qx_k(
    const float* __restrict__ obs, const float* __restrict__ qb1,
    const char* __restrict__ wsb, u16* __restrict__ qxp)
{
  const int tid = threadIdx.x, w = tid >> 6, lane = tid & 63;
  const int nl = lane & 15, kg = lane >> 4;
  const int r0 = blockIdx.x * 16;
  __shared__ __align__(16) u16 sob[16*224];
  for (int i = tid; i < 16*224; i += 512) sob[i] = 0;
  __syncthreads();
  if (tid < 400) {
    int m = tid / 25, c8 = tid % 25;
    const float* op = obs + (size_t)(r0+m)*OBS_ + c8*8;
    f32x4 a = *(const f32x4*)op, b = *(const f32x4*)(op + 4);
    st8_3(sob, m, c8, pack8(a, b));
  }
  __syncthreads();
#pragma unroll
  for (int qi = 0; qi < 2; ++qi) {
    int tq = w + qi*8;
    if (tq < 13) {
      f32x4 acc{0,0,0,0};
#pragma unroll
      for (int ks = 0; ks < 7; ++ks)
        acc = mfma(ldA3(sob, nl, ks*32 + kg*8), ldB(wsb, U_QW1 + tq*14 + ks, lane), acc);
      int n = tq*16 + nl;
      if (n < 200) {
        float b = qb1[n];
#pragma unroll
        for (int i = 0; i < 4; ++i)
          qxp[(size_t)(r0 + kg*4 + i)*OBS_ + n] = f2b(acc[i] + b);
      }
    }
  }
}

// ---------------- prior kernel: mu_p/std_p for all rows (reads h from out) ---
__global__ __launch_bounds__(512) void prior_k(
    const float* __restrict__ pb1, const float* __restrict__ pb2,
    const char* __restrict__ wsb, float* __restrict__ out)
{
  const int tid = threadIdx.x, w = tid >> 6, lane = tid & 63;
  const int nl = lane & 15, kg = lane >> 4;
  const int r0 = blockIdx.x * 16;
  __shared__ __align__(16) u16 shh[16*224];
  __shared__ __align__(16) u16 spp[16*224];
  for (int i = tid; i < 16*224; i += 512) { shh[i] = 0; spp[i] = 0; }
  __syncthreads();
  if (tid < 400) {
    int m = tid / 25, c8 = tid % 25;
    const float* hp = out + (size_t)(r0+m)*OUTC + 150 + c8*8;
    f32x4 a, b;
#pragma unroll
    for (int i = 0; i < 4; ++i) { a[i] = hp[i]; b[i] = hp[4+i]; }
    st8_3(shh, m, c8, pack8(a, b));
  }
  __syncthreads();
#pragma unroll
  for (int qi = 0; qi < 2; ++qi) {
    int tq = w + qi*8;
    if (tq < 13) {
      f32x4 acc{0,0,0,0};
#pragma unroll
      for (int ks = 0; ks < 7; ++ks)
        acc = mfma(ldA3(shh, nl, ks*32 + kg*8), ldB(wsb, U_PW1 + tq*7 + ks, lane), acc);
      int n = tq*16 + nl;
      if (n < 200) {
        float b = pb1[n];
#pragma unroll
        for (int i = 0; i < 4; ++i) {
          float v = acc[i] + b;
          st23(spp, kg*4 + i, n, f2b(v > 0.f ? v : 0.f));
        }
      }
    }
  }
  __syncthreads();
  if (w < 2) {
    f32x4 a0{0,0,0,0}, a1{0,0,0,0};
#pragma unroll
    for (int ks = 0; ks < 7; ++ks) {
      short8 af = ldA3(spp, nl, ks*32 + kg*8);
      a0 = mfma(af, ldB(wsb, U_PW2 + w*7 + ks,     lane), a0);
      a1 = mfma(af, ldB(wsb, U_PW2 + (w+2)*7 + ks, lane), a1);
    }
    int c3 = w*16 + nl;
    if (c3 < 30) {
      float bmu = pb2[c3], bpre = pb2[30 + c3];
#pragma unroll
      for (int i = 0; i < 4; ++i) {
        size_t ob = (size_t)(r0 + kg*4 + i)*OUTC;
        out[ob + c3] = a0[i] + bmu;
        float sp = softplus_(a1[i] + bpre) + 1e-5f;
        out[ob + 30 + c3] = fmaxf(sp, 1e-4f);
      }
    }
  }
}

// ---------------- sequential scan: GRU + posterior chain ---------------------
__global__ __attribute__((amdgpu_waves_per_eu(4, 4))) __launch_bounds__(1024)
void rssm_seq(
    const float* __restrict__ act, const float* __restrict__ noise,
    const float* __restrict__ b_ih, const float* __restrict__ b_hh,
    const float* __restrict__ qb2,
    const u16* __restrict__ qxp, const char* __restrict__ wsb,
    float* __restrict__ out)
{
  const int tid  = threadIdx.x;
  const int w    = tid >> 6;      // wave 0..15
  const int lane = tid & 63;
  const int nl   = lane & 15;
  const int kg   = lane >> 4;
  const int m0   = blockIdx.x * 16;

  // h0/h1: [16][256] stride 512B: h 0..199 | s 200..229 | a 230..235 | zeros
  // sqq/sqx: [16][224] stride 448B
  __shared__ __align__(16) u16 h0 [16*256];
  __shared__ __align__(16) u16 h1 [16*256];
  __shared__ __align__(16) u16 sqq[16*224];
  __shared__ __align__(16) u16 sqx[16*224];

  for (int i = tid; i < 16*256; i += 1024) { h0[i]=0; h1[i]=0; }
  for (int i = tid; i < 16*224; i += 1024) { sqq[i]=0; sqx[i]=0; }

  // P1 role: waves 0..12, job tq = w
  const bool p1v = (w < 13);
  const int  cj  = w*16 + nl;
  const bool cjv = p1v && (cj < 200);
  float bR=0,bZ=0,bI=0,bH=0;
  if (cjv) {
    bR = b_ih[cj]       + b_hh[cj];
    bZ = b_ih[200 + cj] + b_hh[200 + cj];
    bI = b_ih[400 + cj];
    bH = b_hh[400 + cj];
  }
  // P3 role: waves 0,1 (mu tile w, pre tile w+2)
  const bool isP3 = (w < 2);
  const int  c3   = w*16 + nl;
  const bool c3v  = isP3 && (c3 < 30);
  float b3mu=0, b3pre=0;
  if (c3v) { b3mu = qb2[c3]; b3pre = qb2[30 + c3]; }
  // stager role: waves 13..15
  const bool isStage = (w >= 13);
  const int  t2 = (w - 13)*64 + lane;   // 0..191

  __syncthreads();
  // prologue: qx(l=0) -> sqx ; act(l=0) -> h0 (s0=h0=0 already)
  for (int t = tid; t < 400; t += 1024) {
    int m = t / 25, c8 = t % 25;
    short8 v = *(const short8*)(qxp + ((size_t)(m0+m)*LL)*OBS_ + c8*8);
    st8_3(sqx, m, c8, v);
  }
  if (tid < 96) {
    int m = tid / 6, j = tid % 6;
    st27(h0, m, 230 + j, f2b(act[(size_t)(m0+m)*LL*ACT_ + j]));
  }
  __syncthreads();

#pragma unroll 1
  for (int l = 0; l < LL; ++l) {
    u16* hO = (l & 1) ? h1 : h0;
    u16* hN = (l & 1) ? h0 : h1;
    const size_t outB = (size_t)l*OUTC;

    // eps prefetch (waves 0,1; consumed in P3)
    float ep[4] = {0,0,0,0};
    if (c3v) {
      const float* np = noise + (size_t)(m0 + kg*4)*LL*STO + (size_t)l*STO + c3;
#pragma unroll
      for (int i = 0; i < 4; ++i) ep[i] = np[(size_t)i*LL*STO];
    }

    // ================= P1: GRU (waves 0..12) ; stagers load qx/act ==========
    if (p1v) {
      short8 af[9];
#pragma unroll
      for (int ks = 0; ks < 9; ++ks) {
        const int col = (ks < 2) ? (200 + ks*32 + kg*8) : ((ks-2)*32 + kg*8);
        af[ks] = ldA7(hO, nl, col);
      }
      f32x4 aR{0,0,0,0}, aZ{0,0,0,0}, aI{0,0,0,0}, aH{0,0,0,0};
#pragma unroll
      for (int ks = 0; ks < 9; ++ks) {
        aR = mfma(af[ks], ldB(wsb, U_WG + w*9 + ks,      lane), aR);
        aZ = mfma(af[ks], ldB(wsb, U_WG + (13+w)*9 + ks, lane), aZ);
        if (ks < 2) aI = mfma(af[ks], ldB(wsb, U_WG + (26+w)*9 + ks, lane), aI);
        else        aH = mfma(af[ks], ldB(wsb, U_WG + (39+w)*9 + ks, lane), aH);
      }
      if (cj < 200) {
#pragma unroll
        for (int i = 0; i < 4; ++i) {
          int m = kg*4 + i;
          float r = sigm(aR[i] + bR);
          float z = sigm(aZ[i] + bZ);
          float n = tanhf_(aI[i] + bI + r*(aH[i] + bH));
          float hold = b2f(ld27(hO, m, cj));
          float hnew = (1.f - z)*n + z*hold;
          st27(hN, m, cj, f2b(hnew));
          out[(size_t)(m0+m)*LL*OUTC + outB + 150 + cj] = hnew;
        }
      }
    } else if (l + 1 < LL) {
      // stage qx(l+1)… wait: qx(l) already consumed? No: qx(l) is consumed in
      // THIS step's P2, so stage qx for l+1 into sqx is a RACE. Stage into sqx
      // only AFTER P2. Here: stage act(l+1) into hN (safe: P1 writes cols<200).
      if (t2 < 96) {
        int m = t2 / 6, j = t2 % 6;
        st27(hN, m, 230 + j, f2b(act[((size_t)(m0+m)*LL + (l+1))*ACT_ + j]));
      }
    }
    __syncthreads();

    // ================= P2: q1 h-part + qx + relu (waves 0..12) ==============
    if (p1v) {
      short8 g[7];
#pragma unroll
      for (int ks = 0; ks < 7; ++ks) g[ks] = ldA7(hN, nl, ks*32 + kg*8);
      f32x4 aq{0,0,0,0};
#pragma unroll
      for (int ks = 0; ks < 7; ++ks)
        aq = mfma(g[ks], ldB(wsb, U_QW1 + w*14 + 7 + ks, lane), aq);
      if (cj < 200) {
#pragma unroll
        for (int i = 0; i < 4; ++i) {
          int m = kg*4 + i;
          float v = aq[i] + b2f(ld23(sqx, m, cj));
          st23(sqq, m, cj, f2b(v > 0.f ? v : 0.f));
        }
      }
    }
    __syncthreads();

    // ================= P3: q2 heads + reparam (waves 0,1); stage qx(l+1) ====
    if (isP3) {
      f32x4 a0{0,0,0,0}, a1{0,0,0,0};
#pragma unroll
      for (int ks = 0; ks < 7; ++ks) {
        short8 af = ldA3(sqq, nl, ks*32 + kg*8);
        a0 = mfma(af, ldB(wsb, U_QW2 + w*7 + ks,     lane), a0);
        a1 = mfma(af, ldB(wsb, U_QW2 + (w+2)*7 + ks, lane), a1);
      }
      if (c3 < 30) {
#pragma unroll
        for (int i = 0; i < 4; ++i) {
          int m = kg*4 + i;
          size_t ob = (size_t)(m0+m)*LL*OUTC + outB;
          float mu = a0[i] + b3mu;
          float sp = softplus_(a1[i] + b3pre) + 1e-5f;
          float sd = fmaxf(sp, 1e-4f);
          float s = mu + sd*ep[i];
          out[ob +  60 + c3] = mu;
          out[ob +  90 + c3] = sd;
          out[ob + 120 + c3] = s;
          st27(hN, m, 200 + c3, f2b(s));
        }
      }
    } else if (isStage && (l + 1 < LL)) {
      // sqx free now (P2 done) — stage qx(l+1)
      for (int t = t2; t < 400; t += 192) {
        int m = t / 25, c8 = t % 25;
        short8 v = *(const short8*)(qxp + ((size_t)(m0+m)*LL + (l+1))*OBS_ + c8*8);
        st8_3(sqx, m, c8, v);
      }
    }
    __syncthreads();
  }
}

extern "C" void kernel_launch(void* const* d_in, const int* in_sizes, int n_in,
                              void* d_out, int out_size, void* d_ws, size_t ws_size,
                              hipStream_t stream) {
  const float* obs   = (const float*)d_in[0];
  const float* act   = (const float*)d_in[1];
  const float* noise = (const float*)d_in[2];
  const float* W_ih  = (const float*)d_in[3];
  const float* b_ih  = (const float*)d_in[4];
  const float* W_hh  = (const float*)d_in[5];
  const float* b_hh  = (const float*)d_in[6];
  const float* pW1   = (const float*)d_in[7];
  const float* pb1   = (const float*)d_in[8];
  const float* pW2   = (const float*)d_in[9];
  const float* pb2   = (const float*)d_in[10];
  const float* qW1   = (const float*)d_in[11];
  const float* qb1   = (const float*)d_in[12];
  const float* qW2   = (const float*)d_in[13];
  const float* qb2   = (const float*)d_in[14];
  float* out = (float*)d_out;
  u16* qxp = (u16*)((char*)d_ws + QX_OFF);

  pack_w<<<U_TOT, 512, 0, stream>>>(W_ih, W_hh, pW1, qW1, pW2, qW2, (u16*)d_ws);
  qx_k<<<8192, 512, 0, stream>>>(obs, qb1, (const char*)d_ws, qxp);
  rssm_seq<<<128, 1024, 0, stream>>>(act, noise, b_ih, b_hh, qb2,
                                     qxp, (const char*)d_ws, out);
  prior_k<<<8192, 512, 0, stream>>>(pb1, pb2, (const char*)d_ws, out);
}

// Round 5
// 616.918 us; speedup vs baseline: 4.0712x; 2.2101x over previous
//
#include <hip/hip_runtime.h>

// RSSM v5: pack_w + qx_k + prior_k (all verified r4) unchanged.
// rssm_seq rebuilt: 128 blocks x 512 thr (8 waves), M=16 rows, launch_bounds(512,2)
// for a 256-VGPR budget (r3/r4 lesson: 1024-thr kernels get 64 VGPR and spill).
// QW1h+QW2 weights (119KB) cached in LDS at start -> P2/P3 are pure-LDS phases;
// only P1's GRU weights (351KB/step) stream from L2, with full register ILP.
// qx read into registers at step start (no sqx buffer, no stager waves).

typedef unsigned short u16;
typedef unsigned int u32;
typedef __attribute__((ext_vector_type(8))) short short8;
typedef __attribute__((ext_vector_type(4))) float f32x4;

#define LL 64
#define OBS_ 200
#define ACT_ 6
#define STO 30
#define OUTC 350

// packed-weight unit offsets (1 unit = 1KB = 64 lanes x 16B)
#define U_WG   0
#define U_PW1  468
#define U_QW1  559
#define U_PW2  741
#define U_QW2  769
#define U_TOT  797
#define QX_OFF (1u << 20)

__device__ __forceinline__ u16 f2b(float f){
  u32 u = __float_as_uint(f);
  u = (u + 0x7fffu + ((u >> 16) & 1u)) >> 16;   // RNE
  return (u16)u;
}
__device__ __forceinline__ float b2f(u16 h){ return __uint_as_float(((u32)h) << 16); }

// stride-512B tiles (h): swizzle byte ^= (r&7)<<4
__device__ __forceinline__ short8 ldA7(const u16* buf, int r, int colStart){
  return *(const short8*)((const char*)buf + r*512 + ((colStart*2) ^ ((r & 7) << 4)));
}
__device__ __forceinline__ void st27(u16* buf, int r, int c, u16 v){
  *(u16*)((char*)buf + r*512 + ((c*2) ^ ((r & 7) << 4))) = v;
}
__device__ __forceinline__ u16 ld27(const u16* buf, int r, int c){
  return *(const u16*)((const char*)buf + r*512 + ((c*2) ^ ((r & 7) << 4)));
}
// stride-448B tiles (sqq/sob/shh/spp): swizzle byte ^= (r&3)<<4
__device__ __forceinline__ short8 ldA3(const u16* buf, int r, int colStart){
  return *(const short8*)((const char*)buf + r*448 + ((colStart*2) ^ ((r & 3) << 4)));
}
__device__ __forceinline__ void st23(u16* buf, int r, int c, u16 v){
  *(u16*)((char*)buf + r*448 + ((c*2) ^ ((r & 3) << 4))) = v;
}
__device__ __forceinline__ void st8_3(u16* buf, int r, int c8, short8 v){
  *(short8*)((char*)buf + r*448 + ((c8*16) ^ ((r & 3) << 4))) = v;
}
__device__ __forceinline__ short8 ldB(const char* wsb, int unit, int lane){
  return *(const short8*)(wsb + (((size_t)unit) << 10) + ((size_t)lane << 4));
}
__device__ __forceinline__ short8 lwq(const u16* sw, int lu, int lane){
  return *(const short8*)((const char*)sw + ((size_t)lu << 10) + (lane << 4));
}
__device__ __forceinline__ f32x4 mfma(short8 a, short8 b, f32x4 c){
  return __builtin_amdgcn_mfma_f32_16x16x32_bf16(a, b, c, 0, 0, 0);
}
__device__ __forceinline__ float sigm(float x){ return 1.f / (1.f + __expf(-x)); }
__device__ __forceinline__ float tanhf_(float x){
  x = fminf(fmaxf(x, -15.f), 15.f);
  float e = __expf(-2.f * x);
  return (1.f - e) / (1.f + e);
}
__device__ __forceinline__ float softplus_(float x){
  return (x > 20.f) ? x : log1pf(__expf(x));
}
__device__ __forceinline__ short8 pack8(f32x4 a, f32x4 b){
  short8 v;
  v[0]=(short)f2b(a[0]); v[1]=(short)f2b(a[1]); v[2]=(short)f2b(a[2]); v[3]=(short)f2b(a[3]);
  v[4]=(short)f2b(b[0]); v[5]=(short)f2b(b[1]); v[6]=(short)f2b(b[2]); v[7]=(short)f2b(b[3]);
  return v;
}

// ---------------- weight packing (UNCHANGED, verified round 1) ---------------
__global__ __launch_bounds__(512) void pack_w(
    const float* W_ih, const float* W_hh, const float* pW1f, const float* qW1f,
    const float* pW2f, const float* qW2f, u16* wsu)
{
  int u = blockIdx.x;
  int t = threadIdx.x;
  int lane = t >> 3, j = t & 7;
  int nl = lane & 15, kg = lane >> 4;
  float v = 0.f;
  if (u < U_PW1) {                       // WG
    int nt = u / 9, ks = u % 9;
    int k = ks*32 + kg*8 + j;
    int c = nt*16 + nl;
    int grow, part, coff;
    if (c < 208)      { grow = c;            part = 0; coff = c; }
    else if (c < 416) { grow = 200 + (c-208); part = 0; coff = c-208; }
    else if (c < 624) { grow = 400 + (c-416); part = 1; coff = c-416; }
    else              { grow = 400 + (c-624); part = 2; coff = c-624; }
    if (coff < 200) {
      if (k < 36)                  { if (part != 2) v = W_ih[grow*36 + k]; }
      else if (k >= 64 && k < 264) { if (part != 1) v = W_hh[grow*200 + (k-64)]; }
    }
  } else if (u < U_QW1) {                // PW1
    int uu = u - U_PW1; int nt = uu / 7, ks = uu % 7;
    int k = ks*32 + kg*8 + j; int n = nt*16 + nl;
    if (n < 200 && k < 200) v = pW1f[n*200 + k];
  } else if (u < U_PW2) {                // QW1
    int uu = u - U_QW1; int nt = uu / 14, ks = uu % 14;
    int k = ks*32 + kg*8 + j; int n = nt*16 + nl;
    if (n < 200) {
      if (k < 200) v = qW1f[n*400 + k];
      else if (k >= 224 && k < 424) v = qW1f[n*400 + 200 + (k-224)];
    }
  } else {                               // PW2 / QW2
    bool isQ = (u >= U_QW2);
    int uu = u - (isQ ? U_QW2 : U_PW2); int nt = uu / 7, ks = uu % 7;
    int k = ks*32 + kg*8 + j; int c = nt*16 + nl;
    int row = (c < 32) ? c : 30 + (c - 32);
    bool ok = (c < 32) ? (c < 30) : ((c - 32) < 30);
    const float* W = isQ ? qW2f : pW2f;
    if (ok && k < 200) v = W[row*200 + k];
  }
  wsu[((size_t)u << 9) + lane*8 + j] = f2b(v);
}

// ---------------- qx kernel (UNCHANGED, verified round 4) --------------------
__global__ __launch_bounds__(512) void qx_k(
    const float* __restrict__ obs, const float* __restrict__ qb1,
    const char* __restrict__ wsb, u16* __restrict__ qxp)
{
  const int tid = threadIdx.x, w = tid >> 6, lane = tid & 63;
  const int nl = lane & 15, kg = lane >> 4;
  const int r0 = blockIdx.x * 16;
  __shared__ __align__(16) u16 sob[16*224];
  for (int i = tid; i < 16*224; i += 512) sob[i] = 0;
  __syncthreads();
  if (tid < 400) {
    int m = tid / 25, c8 = tid % 25;
    const float* op = obs + (size_t)(r0+m)*OBS_ + c8*8;
    f32x4 a = *(const f32x4*)op, b = *(const f32x4*)(op + 4);
    st8_3(sob, m, c8, pack8(a, b));
  }
  __syncthreads();
#pragma unroll
  for (int qi = 0; qi < 2; ++qi) {
    int tq = w + qi*8;
    if (tq < 13) {
      f32x4 acc{0,0,0,0};
#pragma unroll
      for (int ks = 0; ks < 7; ++ks)
        acc = mfma(ldA3(sob, nl, ks*32 + kg*8), ldB(wsb, U_QW1 + tq*14 + ks, lane), acc);
      int n = tq*16 + nl;
      if (n < 200) {
        float b = qb1[n];
#pragma unroll
        for (int i = 0; i < 4; ++i)
          qxp[(size_t)(r0 + kg*4 + i)*OBS_ + n] = f2b(acc[i] + b);
      }
    }
  }
}

// ---------------- prior kernel (UNCHANGED, verified round 4) -----------------
__global__ __launch_bounds__(512) void prior_k(
    const float* __restrict__ pb1, const float* __restrict__ pb2,
    const char* __restrict__ wsb, float* __restrict__ out)
{
  const int tid = threadIdx.x, w = tid >> 6, lane = tid & 63;
  const int nl = lane & 15, kg = lane >> 4;
  const int r0 = blockIdx.x * 16;
  __shared__ __align__(16) u16 shh[16*224];
  __shared__ __align__(16) u16 spp[16*224];
  for (int i = tid; i < 16*224; i += 512) { shh[i] = 0; spp[i] = 0; }
  __syncthreads();
  if (tid < 400) {
    int m = tid / 25, c8 = tid % 25;
    const float* hp = out + (size_t)(r0+m)*OUTC + 150 + c8*8;
    f32x4 a, b;
#pragma unroll
    for (int i = 0; i < 4; ++i) { a[i] = hp[i]; b[i] = hp[4+i]; }
    st8_3(shh, m, c8, pack8(a, b));
  }
  __syncthreads();
#pragma unroll
  for (int qi = 0; qi < 2; ++qi) {
    int tq = w + qi*8;
    if (tq < 13) {
      f32x4 acc{0,0,0,0};
#pragma unroll
      for (int ks = 0; ks < 7; ++ks)
        acc = mfma(ldA3(shh, nl, ks*32 + kg*8), ldB(wsb, U_PW1 + tq*7 + ks, lane), acc);
      int n = tq*16 + nl;
      if (n < 200) {
        float b = pb1[n];
#pragma unroll
        for (int i = 0; i < 4; ++i) {
          float v = acc[i] + b;
          st23(spp, kg*4 + i, n, f2b(v > 0.f ? v : 0.f));
        }
      }
    }
  }
  __syncthreads();
  if (w < 2) {
    f32x4 a0{0,0,0,0}, a1{0,0,0,0};
#pragma unroll
    for (int ks = 0; ks < 7; ++ks) {
      short8 af = ldA3(spp, nl, ks*32 + kg*8);
      a0 = mfma(af, ldB(wsb, U_PW2 + w*7 + ks,     lane), a0);
      a1 = mfma(af, ldB(wsb, U_PW2 + (w+2)*7 + ks, lane), a1);
    }
    int c3 = w*16 + nl;
    if (c3 < 30) {
      float bmu = pb2[c3], bpre = pb2[30 + c3];
#pragma unroll
      for (int i = 0; i < 4; ++i) {
        size_t ob = (size_t)(r0 + kg*4 + i)*OUTC;
        out[ob + c3] = a0[i] + bmu;
        float sp = softplus_(a1[i] + bpre) + 1e-5f;
        out[ob + 30 + c3] = fmaxf(sp, 1e-4f);
      }
    }
  }
}

// ---------------- sequential scan v5 -----------------------------------------
__global__ __launch_bounds__(512, 2) void rssm_seq(
    const float* __restrict__ act, const float* __restrict__ noise,
    const float* __restrict__ b_ih, const float* __restrict__ b_hh,
    const float* __restrict__ qb2,
    const u16* __restrict__ qxp, const char* __restrict__ wsb,
    float* __restrict__ out)
{
  const int tid  = threadIdx.x;
  const int w    = tid >> 6;      // wave 0..7
  const int lane = tid & 63;
  const int nl   = lane & 15;
  const int kg   = lane >> 4;
  const int m0   = blockIdx.x * 16;

  // LDS weight cache: 119 units = QW1h (tq*7+ks, 91) then QW2 (nt*7+ks, 28)
  __shared__ __align__(16) u16 swq[119*512];
  // h0/h1: [16][256] stride 512B: h 0..199 | s 200..229 | a 230..235 | zeros
  __shared__ __align__(16) u16 h0 [16*256];
  __shared__ __align__(16) u16 h1 [16*256];
  __shared__ __align__(16) u16 sqq[16*224];   // stride 448B

  for (int i = tid; i < 16*256; i += 512) { h0[i]=0; h1[i]=0; }
  for (int i = tid; i < 16*224; i += 512) sqq[i]=0;
  // load LDS weight cache (one-time, 119KB)
  for (int c = tid; c < 119*64; c += 512) {
    int lu = c >> 6, l16 = c & 63;
    int gu = (lu < 91) ? (U_QW1 + (lu/7)*14 + 7 + (lu%7)) : (U_QW2 + (lu - 91));
    *(short8*)((char*)swq + (size_t)c*16) =
        *(const short8*)(wsb + ((size_t)gu << 10) + (l16 << 4));
  }

  // ---- roles ----
  // P1/P2 job1: tq = w (all 8 waves). job2 (waves 3..7): tq2 = w+5 (8..12).
  const int  cj  = w*16 + nl;                       // < 128, always valid
  const bool j2  = (w >= 3);
  const int  tq2 = w + 5;
  const int  cj2 = tq2*16 + nl;
  const bool cj2v = j2 && (cj2 < 200);
  const float bR1 = b_ih[cj]       + b_hh[cj];
  const float bZ1 = b_ih[200 + cj] + b_hh[200 + cj];
  const float bI1 = b_ih[400 + cj];
  const float bH1 = b_hh[400 + cj];
  float bR2=0,bZ2=0,bI2=0,bH2=0;
  if (cj2v) {
    bR2 = b_ih[cj2] + b_hh[cj2];
    bZ2 = b_ih[200+cj2] + b_hh[200+cj2];
    bI2 = b_ih[400+cj2];
    bH2 = b_hh[400+cj2];
  }
  // P3: waves 0,1 (mu tile w, pre tile w+2 of QW2)
  const bool isP3 = (w < 2);
  const int  c3   = w*16 + nl;
  const bool c3v  = isP3 && (c3 < 30);
  float b3mu=0, b3pre=0;
  if (c3v) { b3mu = qb2[c3]; b3pre = qb2[30 + c3]; }
  // act stagers: waves 2,3 (96 lanes)
  const int  t2 = (w - 2)*64 + lane;
  const bool isAct = (w == 2 || w == 3) && (t2 < 96);

  __syncthreads();
  // prologue: act(l=0) -> h0 cols 230..235 (s0=h0=0 already)
  if (tid < 96) {
    int m = tid / 6, j = tid % 6;
    st27(h0, m, 230 + j, f2b(act[(size_t)(m0+m)*LL*ACT_ + j]));
  }
  __syncthreads();

#pragma unroll 1
  for (int l = 0; l < LL; ++l) {
    u16* hO = (l & 1) ? h1 : h0;
    u16* hN = (l & 1) ? h0 : h1;
    const size_t outB = (size_t)l*OUTC;

    // ---- step-start prefetches (consumed 1-2 phases later) ----
    float ep[4] = {0,0,0,0};
    if (c3v) {
      const float* np = noise + (size_t)(m0 + kg*4)*LL*STO + (size_t)l*STO + c3;
#pragma unroll
      for (int i = 0; i < 4; ++i) ep[i] = np[(size_t)i*LL*STO];
    }
    float qx1[4], qx2[4] = {0,0,0,0};
#pragma unroll
    for (int i = 0; i < 4; ++i)
      qx1[i] = b2f(qxp[((size_t)(m0 + kg*4 + i)*LL + l)*OBS_ + cj]);
    if (cj2v) {
#pragma unroll
      for (int i = 0; i < 4; ++i)
        qx2[i] = b2f(qxp[((size_t)(m0 + kg*4 + i)*LL + l)*OBS_ + cj2]);
    }
    float av = 0.f;
    if (isAct && (l + 1 < LL))
      av = act[((size_t)(m0 + t2/6)*LL + (l+1))*ACT_ + (t2 % 6)];

    // ================= P1: GRU gates (L2 weight stream) =====================
    short8 a9[9];
#pragma unroll
    for (int ks = 0; ks < 9; ++ks) {
      const int col = (ks < 2) ? (200 + ks*32 + kg*8) : ((ks-2)*32 + kg*8);
      a9[ks] = ldA7(hO, nl, col);
    }
    if (!j2) {
      f32x4 aR{0,0,0,0}, aZ{0,0,0,0}, aI{0,0,0,0}, aH{0,0,0,0};
#pragma unroll
      for (int ks = 0; ks < 9; ++ks) {
        aR = mfma(a9[ks], ldB(wsb, U_WG + w*9 + ks,      lane), aR);
        aZ = mfma(a9[ks], ldB(wsb, U_WG + (13+w)*9 + ks, lane), aZ);
        if (ks < 2) aI = mfma(a9[ks], ldB(wsb, U_WG + (26+w)*9 + ks, lane), aI);
        else        aH = mfma(a9[ks], ldB(wsb, U_WG + (39+w)*9 + ks, lane), aH);
      }
#pragma unroll
      for (int i = 0; i < 4; ++i) {
        int m = kg*4 + i;
        float r = sigm(aR[i] + bR1);
        float z = sigm(aZ[i] + bZ1);
        float n = tanhf_(aI[i] + bI1 + r*(aH[i] + bH1));
        float hold = b2f(ld27(hO, m, cj));
        float hnew = (1.f - z)*n + z*hold;
        st27(hN, m, cj, f2b(hnew));
        out[(size_t)(m0+m)*LL*OUTC + outB + 150 + cj] = hnew;
      }
    } else {
      f32x4 aR1{0,0,0,0}, aZ1{0,0,0,0}, aI1{0,0,0,0}, aH1{0,0,0,0};
      f32x4 aR2{0,0,0,0}, aZ2{0,0,0,0}, aI2{0,0,0,0}, aH2{0,0,0,0};
#pragma unroll
      for (int ks = 0; ks < 9; ++ks) {
        short8 bRa = ldB(wsb, U_WG + w*9 + ks,        lane);
        short8 bRb = ldB(wsb, U_WG + tq2*9 + ks,      lane);
        short8 bZa = ldB(wsb, U_WG + (13+w)*9 + ks,   lane);
        short8 bZb = ldB(wsb, U_WG + (13+tq2)*9 + ks, lane);
        aR1 = mfma(a9[ks], bRa, aR1); aR2 = mfma(a9[ks], bRb, aR2);
        aZ1 = mfma(a9[ks], bZa, aZ1); aZ2 = mfma(a9[ks], bZb, aZ2);
        if (ks < 2) {
          short8 bIa = ldB(wsb, U_WG + (26+w)*9 + ks,   lane);
          short8 bIb = ldB(wsb, U_WG + (26+tq2)*9 + ks, lane);
          aI1 = mfma(a9[ks], bIa, aI1); aI2 = mfma(a9[ks], bIb, aI2);
        } else {
          short8 bHa = ldB(wsb, U_WG + (39+w)*9 + ks,   lane);
          short8 bHb = ldB(wsb, U_WG + (39+tq2)*9 + ks, lane);
          aH1 = mfma(a9[ks], bHa, aH1); aH2 = mfma(a9[ks], bHb, aH2);
        }
      }
#pragma unroll
      for (int i = 0; i < 4; ++i) {
        int m = kg*4 + i;
        float r = sigm(aR1[i] + bR1);
        float z = sigm(aZ1[i] + bZ1);
        float n = tanhf_(aI1[i] + bI1 + r*(aH1[i] + bH1));
        float hold = b2f(ld27(hO, m, cj));
        float hnew = (1.f - z)*n + z*hold;
        st27(hN, m, cj, f2b(hnew));
        out[(size_t)(m0+m)*LL*OUTC + outB + 150 + cj] = hnew;
      }
      if (cj2 < 200) {
#pragma unroll
        for (int i = 0; i < 4; ++i) {
          int m = kg*4 + i;
          float r = sigm(aR2[i] + bR2);
          float z = sigm(aZ2[i] + bZ2);
          float n = tanhf_(aI2[i] + bI2 + r*(aH2[i] + bH2));
          float hold = b2f(ld27(hO, m, cj2));
          float hnew = (1.f - z)*n + z*hold;
          st27(hN, m, cj2, f2b(hnew));
          out[(size_t)(m0+m)*LL*OUTC + outB + 150 + cj2] = hnew;
        }
      }
    }
    __syncthreads();

    // ================= P2: q1h GEMM (LDS weights) ===========================
    {
      short8 g[7];
#pragma unroll
      for (int ks = 0; ks < 7; ++ks) g[ks] = ldA7(hN, nl, ks*32 + kg*8);
      f32x4 aq1{0,0,0,0}, aq2{0,0,0,0};
#pragma unroll
      for (int ks = 0; ks < 7; ++ks) {
        aq1 = mfma(g[ks], lwq(swq, w*7 + ks, lane), aq1);
        if (j2) aq2 = mfma(g[ks], lwq(swq, tq2*7 + ks, lane), aq2);
      }
#pragma unroll
      for (int i = 0; i < 4; ++i) {
        int m = kg*4 + i;
        float v = aq1[i] + qx1[i];
        st23(sqq, m, cj, f2b(v > 0.f ? v : 0.f));
      }
      if (cj2v) {
#pragma unroll
        for (int i = 0; i < 4; ++i) {
          int m = kg*4 + i;
          float v = aq2[i] + qx2[i];
          st23(sqq, m, cj2, f2b(v > 0.f ? v : 0.f));
        }
      }
    }
    __syncthreads();

    // ================= P3: q2 heads + reparam (waves 0,1; LDS weights) ======
    if (isP3) {
      f32x4 a0{0,0,0,0}, a1{0,0,0,0};
#pragma unroll
      for (int ks = 0; ks < 7; ++ks) {
        short8 af = ldA3(sqq, nl, ks*32 + kg*8);
        a0 = mfma(af, lwq(swq, 91 + w*7 + ks,     lane), a0);
        a1 = mfma(af, lwq(swq, 91 + (w+2)*7 + ks, lane), a1);
      }
      if (c3 < 30) {
#pragma unroll
        for (int i = 0; i < 4; ++i) {
          int m = kg*4 + i;
          size_t ob = (size_t)(m0+m)*LL*OUTC + outB;
          float mu = a0[i] + b3mu;
          float sp = softplus_(a1[i] + b3pre) + 1e-5f;
          float sd = fmaxf(sp, 1e-4f);
          float s = mu + sd*ep[i];
          out[ob +  60 + c3] = mu;
          out[ob +  90 + c3] = sd;
          out[ob + 120 + c3] = s;
          st27(hN, m, 200 + c3, f2b(s));
        }
      }
    } else if (isAct && (l + 1 < LL)) {
      st27(hN, t2/6, 230 + (t2 % 6), f2b(av));
    }
    __syncthreads();
  }
}

extern "C" void kernel_launch(void* const* d_in, const int* in_sizes, int n_in,
                              void* d_out, int out_size, void* d_ws, size_t ws_size,
                              hipStream_t stream) {
  const float* obs   = (const float*)d_in[0];
  const float* act   = (const float*)d_in[1];
  const float* noise = (const float*)d_in[2];
  const float* W_ih  = (const float*)d_in[3];
  const float* b_ih  = (const float*)d_in[4];
  const float* W_hh  = (const float*)d_in[5];
  const float* b_hh  = (const float*)d_in[6];
  const float* pW1   = (const float*)d_in[7];
  const float* pb1   = (const float*)d_in[8];
  const float* pW2   = (const float*)d_in[9];
  const float* pb2   = (const float*)d_in[10];
  const float* qW1   = (const float*)d_in[11];
  const float* qb1   = (const float*)d_in[12];
  const float* qW2   = (const float*)d_in[13];
  const float* qb2   = (const float*)d_in[14];
  float* out = (float*)d_out;
  u16* qxp = (u16*)((char*)d_ws + QX_OFF);

  pack_w<<<U_TOT, 512, 0, stream>>>(W_ih, W_hh, pW1, qW1, pW2, qW2, (u16*)d_ws);
  qx_k<<<8192, 512, 0, stream>>>(obs, qb1, (const char*)d_ws, qxp);
  rssm_seq<<<128, 512, 0, stream>>>(act, noise, b_ih, b_hh, qb2,
                                    qxp, (const char*)d_ws, out);
  prior_k<<<8192, 512, 0, stream>>>(pb1, pb2, (const char*)d_ws, out);
}